// Round 1
// baseline (351.694 us; speedup 1.0000x reference)
//
#include <hip/hip_runtime.h>

// Problem constants (from reference)
#define NC 32768
#define ND 1024
#define NB 16384
#define KEEP 0.95f
#define OMK  0.05f   // 1 - keep
#define KCAP 16      // per-class sample-list capacity (counts ~Poisson(0.5); P(>=16) ~ 0)

// Kernel 1: count occurrences per class and scatter sample indices into
// per-class lists. Order within a list is arbitrary; the sample index itself
// encodes batch order, which is what the EMA weights need.
__global__ void count_scatter_kernel(const int* __restrict__ the_class,
                                     int* __restrict__ counts,
                                     int* __restrict__ class_list) {
    int i = blockIdx.x * blockDim.x + threadIdx.x;
    if (i < NB) {
        int c = the_class[i];
        int pos = atomicAdd(&counts[c], 1);
        if (pos < KCAP) class_list[c * KCAP + pos] = i;
    }
}

// Kernel 2: fused EMA + L1 loss. One wave (64 lanes) per row c.
// new_s[c,:] = s[c,:]*keep^cnt + sum_j w_j * logits[idx_j,:]
// w_j = (1-keep)*keep^{#later same-class occurrences}
// loss += sum_d |new_s - t| ; final scale 1/NC.
__global__ __launch_bounds__(256) void loss_kernel(
    const float* __restrict__ s_logits,
    const float* __restrict__ t_logits,
    const float* __restrict__ logits,
    const int*   __restrict__ counts,
    const int*   __restrict__ class_list,
    float* __restrict__ out) {

    const int wave = threadIdx.x >> 6;   // 0..3
    const int lane = threadIdx.x & 63;
    const int c = blockIdx.x * 4 + wave;

    const int cnt = counts[c];

    // decay = keep^cnt (binary exponentiation; cnt is small)
    float decay;
    {
        float base = KEEP, r = 1.0f;
        int e = cnt;
        while (e > 0) { if (e & 1) r *= base; base *= base; e >>= 1; }
        decay = r;
    }

    const int m = cnt < KCAP ? cnt : KCAP;

    // Lane j (< m) owns list entry j: its sample index and EMA weight.
    int myidx = 0x7fffffff;
    if (lane < m) myidx = class_list[c * KCAP + lane];
    int r_later = 0;
    for (int l = 0; l < m; ++l) {
        int other = __shfl(myidx, l);
        if (other > myidx) r_later++;
    }
    float myw = OMK;
    for (int k = 0; k < r_later; ++k) myw *= KEEP;

    const float4* s4 = (const float4*)(s_logits + (size_t)c * ND);
    const float4* t4 = (const float4*)(t_logits + (size_t)c * ND);

    float lsum = 0.0f;
    #pragma unroll
    for (int k = 0; k < 4; ++k) {
        const int q = lane + k * 64;            // float4 index within the row
        float4 sv = s4[q];
        float4 acc;
        acc.x = sv.x * decay;
        acc.y = sv.y * decay;
        acc.z = sv.z * decay;
        acc.w = sv.w * decay;
        for (int j = 0; j < m; ++j) {
            const int   ij = __shfl(myidx, j);
            const float wj = __shfl(myw, j);
            const float4* l4 = (const float4*)(logits + (size_t)ij * ND);
            float4 lv = l4[q];
            acc.x += wj * lv.x;
            acc.y += wj * lv.y;
            acc.z += wj * lv.z;
            acc.w += wj * lv.w;
        }
        float4 tv = t4[q];
        lsum += fabsf(acc.x - tv.x) + fabsf(acc.y - tv.y) +
                fabsf(acc.z - tv.z) + fabsf(acc.w - tv.w);
    }

    // wave reduction (64 lanes)
    #pragma unroll
    for (int off = 32; off > 0; off >>= 1) lsum += __shfl_down(lsum, off);

    __shared__ float wsum[4];
    if (lane == 0) wsum[wave] = lsum;
    __syncthreads();
    if (threadIdx.x == 0) {
        float total = (wsum[0] + wsum[1] + wsum[2] + wsum[3]) * (1.0f / NC);
        atomicAdd(out, total);
    }
}

extern "C" void kernel_launch(void* const* d_in, const int* in_sizes, int n_in,
                              void* d_out, int out_size, void* d_ws, size_t ws_size,
                              hipStream_t stream) {
    const float* s_logits  = (const float*)d_in[0];
    const float* t_logits  = (const float*)d_in[1];
    const float* logits    = (const float*)d_in[2];
    const int*   the_class = (const int*)d_in[3];
    float* out = (float*)d_out;

    int* counts     = (int*)d_ws;          // NC ints
    int* class_list = counts + NC;         // NC*KCAP ints (~2 MB total ws)

    hipMemsetAsync(counts, 0, NC * sizeof(int), stream);
    hipMemsetAsync(d_out, 0, sizeof(float), stream);

    count_scatter_kernel<<<NB / 256, 256, 0, stream>>>(the_class, counts, class_list);
    loss_kernel<<<NC / 4, 256, 0, stream>>>(s_logits, t_logits, logits,
                                            counts, class_list, out);
}

// Round 2
// 335.907 us; speedup vs baseline: 1.0470x; 1.0470x over previous
//
#include <hip/hip_runtime.h>

// Problem constants (from reference)
#define NC 32768
#define ND 1024
#define NQ 256    // float4 chunks per row (ND/4)
#define NB 16384
#define KEEP 0.95f
#define OMK  0.05f   // 1 - keep
#define KCAP 16      // per-class sample-list cap; P(Poisson(0.5) >= 17) ~ 1e-19
#define RPB 8        // rows per block in loss kernel

// Kernel 1: count occurrences per class, scatter sample indices into
// per-class lists (order arbitrary; the index itself encodes batch order).
__global__ void count_scatter_kernel(const int* __restrict__ the_class,
                                     int* __restrict__ counts,
                                     int* __restrict__ idx_list) {
    int i = blockIdx.x * blockDim.x + threadIdx.x;
    if (i < NB) {
        int c = the_class[i];
        int pos = atomicAdd(&counts[c], 1);
        if (pos < KCAP) idx_list[c * KCAP + pos] = i;
    }
}

// Kernel 2: per-class EMA metadata. One thread per class:
// decay[c] = keep^cnt; elist[c][j] = {sample_idx, (1-keep)*keep^{#later occ}}
__global__ void wprep_kernel(const int* __restrict__ counts,
                             const int* __restrict__ idx_list,
                             float* __restrict__ decays,
                             int2* __restrict__ elist) {
    int c = blockIdx.x * blockDim.x + threadIdx.x;
    int cnt = counts[c];
    // decay = keep^cnt via binary exponentiation
    float base = KEEP, r = 1.0f;
    for (int e = cnt; e > 0; e >>= 1) { if (e & 1) r *= base; base *= base; }
    decays[c] = r;
    int m = cnt < KCAP ? cnt : KCAP;
    int idx[KCAP];
    for (int j = 0; j < m; ++j) idx[j] = idx_list[c * KCAP + j];
    for (int j = 0; j < m; ++j) {
        int later = 0;
        for (int l = 0; l < m; ++l) later += (idx[l] > idx[j]);
        float w = OMK;
        for (int k = 0; k < later; ++k) w *= KEEP;
        int2 e; e.x = idx[j]; e.y = __float_as_int(w);
        elist[c * KCAP + j] = e;
    }
}

// Kernel 3: fused EMA + L1 loss. Block = 256 threads handles RPB rows;
// thread q owns float4 column q of each row. All s/t loads for the block's
// rows are issued up front (16 outstanding 1KB wave-loads) for MLP.
__global__ __launch_bounds__(256) void loss_kernel(
    const float* __restrict__ s_logits,
    const float* __restrict__ t_logits,
    const float* __restrict__ logits,
    const int*   __restrict__ counts,
    const float* __restrict__ decays,
    const int2*  __restrict__ elist,
    float* __restrict__ out) {

    const int q  = threadIdx.x;        // 0..255 float4 column
    const int c0 = blockIdx.x * RPB;

    const float4* s4 = (const float4*)s_logits;
    const float4* t4 = (const float4*)t_logits;
    const float4* l4 = (const float4*)logits;

    float4 sv[RPB], tv[RPB];
    #pragma unroll
    for (int r = 0; r < RPB; ++r) sv[r] = s4[(size_t)(c0 + r) * NQ + q];
    #pragma unroll
    for (int r = 0; r < RPB; ++r) tv[r] = t4[(size_t)(c0 + r) * NQ + q];

    float dec[RPB]; int m[RPB];
    #pragma unroll
    for (int r = 0; r < RPB; ++r) {
        dec[r] = decays[c0 + r];
        int cnt = counts[c0 + r];
        m[r] = cnt < KCAP ? cnt : KCAP;
    }

    float lsum = 0.0f;
    #pragma unroll
    for (int r = 0; r < RPB; ++r) {
        const int c = c0 + r;
        float4 acc;
        acc.x = sv[r].x * dec[r];
        acc.y = sv[r].y * dec[r];
        acc.z = sv[r].z * dec[r];
        acc.w = sv[r].w * dec[r];
        for (int j = 0; j < m[r]; ++j) {
            int2 e = elist[c * KCAP + j];
            const float w = __int_as_float(e.y);
            float4 lv = l4[(size_t)e.x * NQ + q];
            acc.x = fmaf(w, lv.x, acc.x);
            acc.y = fmaf(w, lv.y, acc.y);
            acc.z = fmaf(w, lv.z, acc.z);
            acc.w = fmaf(w, lv.w, acc.w);
        }
        lsum += fabsf(acc.x - tv[r].x) + fabsf(acc.y - tv[r].y) +
                fabsf(acc.z - tv[r].z) + fabsf(acc.w - tv[r].w);
    }

    // wave reduction (64 lanes) then cross-wave via LDS
    #pragma unroll
    for (int off = 32; off > 0; off >>= 1) lsum += __shfl_down(lsum, off);
    __shared__ float wsum[4];
    const int wave = threadIdx.x >> 6, lane = threadIdx.x & 63;
    if (lane == 0) wsum[wave] = lsum;
    __syncthreads();
    if (threadIdx.x == 0) {
        float total = (wsum[0] + wsum[1] + wsum[2] + wsum[3]) * (1.0f / NC);
        atomicAdd(out, total);
    }
}

extern "C" void kernel_launch(void* const* d_in, const int* in_sizes, int n_in,
                              void* d_out, int out_size, void* d_ws, size_t ws_size,
                              hipStream_t stream) {
    const float* s_logits  = (const float*)d_in[0];
    const float* t_logits  = (const float*)d_in[1];
    const float* logits    = (const float*)d_in[2];
    const int*   the_class = (const int*)d_in[3];
    float* out = (float*)d_out;

    // workspace layout (8B-aligned segments)
    int*   counts   = (int*)d_ws;                      // NC ints   (128 KB)
    int*   idx_list = counts + NC;                     // NC*KCAP   (2 MB)
    float* decays   = (float*)(idx_list + NC * KCAP);  // NC floats (128 KB)
    int2*  elist    = (int2*)(decays + NC);            // NC*KCAP int2 (4 MB)

    hipMemsetAsync(counts, 0, NC * sizeof(int), stream);
    hipMemsetAsync(d_out, 0, sizeof(float), stream);

    count_scatter_kernel<<<NB / 256, 256, 0, stream>>>(the_class, counts, idx_list);
    wprep_kernel<<<NC / 256, 256, 0, stream>>>(counts, idx_list, decays, elist);
    loss_kernel<<<NC / RPB, 256, 0, stream>>>(s_logits, t_logits, logits,
                                              counts, decays, elist, out);
}